// Round 12
// baseline (352.292 us; speedup 1.0000x reference)
//
#include <hip/hip_runtime.h>
#include <hip/hip_bf16.h>

#define OUT_STRIDE 384
#define EPSV 1e-9f
#define BSH 9
#define BS 512             // nodes per bucket
#define NBMAX 512
#define CH 4096            // edges per multisplit chunk
#define XS 136

typedef __attribute__((ext_vector_type(8))) short bf16x8;
typedef __attribute__((ext_vector_type(4))) float f32x4;

static __device__ __forceinline__ unsigned short f2bf(float f) {
    __hip_bfloat16 h = __float2bfloat16(f);
    return *reinterpret_cast<unsigned short*>(&h);
}

// ---------------- multisplit (fixed-capacity buckets) + feature pack ----------------
__global__ __launch_bounds__(256)
void multisplit_pack_kernel(const int* __restrict__ src, const int* __restrict__ dst,
                            const float* __restrict__ w, int* __restrict__ bcur,
                            int2* __restrict__ edw, unsigned short* __restrict__ dlu,
                            int E, int CAP,
                            const float* __restrict__ features,
                            unsigned short* __restrict__ featb, long n4) {
    __shared__ int hist[NBMAX], scan_[NBMAX], gbase[NBMAX], lcur[NBMAX];
    __shared__ int recS[CH * 3];
    __shared__ int wt[4];
    const int t = threadIdx.x;
    const int lane = t & 63, wv = t >> 6;
    const int c0 = blockIdx.x * CH;
    const int cnt_total = min(CH, E - c0);

    for (int i = t; i < NBMAX; i += 256) hist[i] = 0;
    __syncthreads();
    #pragma unroll
    for (int p = 0; p < CH / 256; ++p) {
        int i = c0 + p * 256 + t;
        if (i < E) atomicAdd(&hist[dst[i] >> BSH], 1);
    }
    __syncthreads();
    {   // exclusive scan of hist[0..NBMAX)
        int b0 = 2 * t, b1 = 2 * t + 1;
        int h0 = hist[b0], h1 = hist[b1];
        int s = h0 + h1;
        int inc = s;
        #pragma unroll
        for (int d = 1; d < 64; d <<= 1) { int u = __shfl_up(inc, d); if (lane >= d) inc += u; }
        if (lane == 63) wt[wv] = inc;
        __syncthreads();
        int base = 0;
        for (int w2 = 0; w2 < wv; ++w2) base += wt[w2];
        int ex = base + inc - s;
        scan_[b0] = ex;
        scan_[b1] = ex + h0;
    }
    __syncthreads();
    for (int i = t; i < NBMAX; i += 256) {
        if (hist[i] > 0) gbase[i] = atomicAdd(&bcur[i], hist[i]);
        lcur[i] = scan_[i];
    }
    __syncthreads();
    #pragma unroll
    for (int p = 0; p < CH / 256; ++p) {
        int i = c0 + p * 256 + t;
        if (i < E) {
            int d = dst[i];
            int b = d >> BSH;
            int j = atomicAdd(&lcur[b], 1);
            recS[3 * j]     = src[i];
            recS[3 * j + 1] = d;
            recS[3 * j + 2] = __float_as_int(w[i]);
        }
    }
    __syncthreads();
    #pragma unroll
    for (int p = 0; p < CH / 256; ++p) {
        int j = p * 256 + t;
        if (j < cnt_total) {
            int d = recS[3 * j + 1];
            int b = d >> BSH;
            int g = gbase[b] + (j - scan_[b]);
            if (g < CAP) {                         // overflow clamp (deterministic)
                long gp = (long)b * CAP + g;
                edw[gp] = make_int2(recS[3 * j], recS[3 * j + 2]);
                dlu[gp] = (unsigned short)(d - (b << BSH));
            }
        }
    }
    // independent stream: pack features f32 -> bf16
    long gid = blockIdx.x * blockDim.x + threadIdx.x;
    long stride = (long)gridDim.x * blockDim.x;
    for (long p = gid; p < n4; p += stride) {
        float4 v = ((const float4*)features)[p];
        ushort4 o;
        o.x = f2bf(v.x); o.y = f2bf(v.y); o.z = f2bf(v.z); o.w = f2bf(v.w);
        *(ushort4*)&featb[p * 4] = o;
    }
}

// ---------------- per-bucket CSR build (LDS cursors) ----------------
__global__ __launch_bounds__(256)
void bucket_csr_kernel(const int2* __restrict__ edw, const unsigned short* __restrict__ dlu,
                       const int* __restrict__ bcur,
                       int* __restrict__ off, int* __restrict__ deg,
                       int2* __restrict__ ed, int N, int CAP) {
    __shared__ int h[BS];
    __shared__ int wt[4];
    const int b = blockIdx.x;
    const int t = threadIdx.x;
    const int lane = t & 63, wv = t >> 6;
    const int cnt = min(bcur[b], CAP);
    const long base = (long)b * CAP;
    const int n0 = b << BSH;
    const int nn = min(BS, N - n0);

    for (int i = t; i < BS; i += 256) h[i] = 0;
    __syncthreads();
    for (int i = t; i < cnt; i += 256) atomicAdd(&h[dlu[base + i]], 1);
    __syncthreads();
    {
        int j0 = 2 * t;
        int l0 = h[j0], l1 = h[j0 + 1];
        int s = l0 + l1;
        int inc = s;
        #pragma unroll
        for (int d = 1; d < 64; d <<= 1) { int u = __shfl_up(inc, d); if (lane >= d) inc += u; }
        if (lane == 63) wt[wv] = inc;
        __syncthreads();
        int base_ = 0;
        for (int w2 = 0; w2 < wv; ++w2) base_ += wt[w2];
        int ex = base_ + inc - s;
        int e0 = ex, e1 = ex + l0;
        __syncthreads();
        h[j0] = e0; h[j0 + 1] = e1;
        if (j0 < nn)     { off[n0 + j0]     = (int)(base + e0); deg[n0 + j0]     = l0; }
        if (j0 + 1 < nn) { off[n0 + j0 + 1] = (int)(base + e1); deg[n0 + j0 + 1] = l1; }
    }
    __syncthreads();
    for (int i = t; i < cnt; i += 256) {
        int d = dlu[base + i];
        int pos = atomicAdd(&h[d], 1);
        ed[base + pos] = edw[base + i];
    }
}

// ---------------- helpers ----------------
__device__ __forceinline__ void acc8(float* a, int4 r, float w) {
    #pragma unroll
    for (int j = 0; j < 4; ++j) {
        int bits = (&r.x)[j];
        float f0 = __int_as_float(bits << 16);
        float f1 = __int_as_float(bits & 0xffff0000);
        a[2 * j]     += f0 * w;
        a[2 * j + 1] += f1 * w;
    }
}

__device__ __forceinline__ int2 nt_ld_int2(const int2* p) {
    long v = __builtin_nontemporal_load((const long*)p);
    int2 r; r.x = (int)(v & 0xffffffffL); r.y = (int)(((unsigned long)v) >> 32);
    return r;
}

__device__ __forceinline__ void stage_W_512(const float* __restrict__ Wf_hop, short* Wl, int tid) {
    const float4* W4 = (const float4*)Wf_hop;
    for (int idx = tid; idx < 128 * 32; idx += 512) {
        float4 v = W4[idx];
        int row = idx >> 5;
        int col = (idx & 31) * 4;
        short* p = &Wl[row * XS + col];
        p[0] = f2bf(v.x); p[1] = f2bf(v.y); p[2] = f2bf(v.z); p[3] = f2bf(v.w);
    }
}

// ---------------- fused: gather 64-node tile into LDS + MFMA transform + LN ----------------
// 512 threads (8 waves). DO_GATHER: phase1 pulls rows via CSR (writing rowout if given),
// else stages rows from xsrc directly. Phase2: col-split MFMA (wave = 16 rows x 64 cols).
__global__ __launch_bounds__(512)
void fusedT_kernel(const unsigned short* __restrict__ xsrc,
                   const int* __restrict__ off, const int* __restrict__ deg,
                   const int2* __restrict__ ed,
                   const float* __restrict__ Dn,
                   const float* __restrict__ Wf_hop,
                   const float* __restrict__ bp, const float* __restrict__ sp,
                   const float* __restrict__ op,
                   unsigned short* __restrict__ rowout,   // h1b or nullptr
                   float* __restrict__ out, int ocol, int N, int DO_GATHER)
{
    __shared__ __attribute__((aligned(16))) short Wl[128 * XS];
    __shared__ __attribute__((aligned(16))) short Xl[64 * XS];
    __shared__ float sums[64][2], ssqs[64][2];
    __shared__ int cur;
    const int tid = threadIdx.x;
    const int lane = tid & 63;
    const int n0 = blockIdx.x * 64;

    if (tid == 0) cur = 0;
    stage_W_512(Wf_hop, Wl, tid);
    __syncthreads();

    // ---- phase 1: fill Xl[64][XS] with bf16 rows ----
    if (DO_GATHER) {
        const int g2 = lane >> 4;
        const int l = lane & 15;
        const unsigned short* Xc = xsrc + 8 * l;
        for (;;) {
            int q;
            if (lane == 0) q = atomicAdd(&cur, 1);
            q = __shfl(q, 0);
            if (q >= 64) break;
            const int n = n0 + q;
            if (n >= N) {
                if (g2 == 0) *(int4*)&Xl[q * XS + 8 * l] = make_int4(0, 0, 0, 0);
                continue;
            }
            const int beg = __builtin_nontemporal_load(&off[n]);
            const int end = beg + __builtin_nontemporal_load(&deg[n]);
            float a[8] = {0.f, 0.f, 0.f, 0.f, 0.f, 0.f, 0.f, 0.f};
            int i = beg + g2;
            for (; i + 12 < end; i += 16) {
                int2 e0 = nt_ld_int2(&ed[i]);
                int2 e1 = nt_ld_int2(&ed[i + 4]);
                int2 e2 = nt_ld_int2(&ed[i + 8]);
                int2 e3 = nt_ld_int2(&ed[i + 12]);
                int4 r0 = *(const int4*)(Xc + (long)e0.x * 128);
                int4 r1 = *(const int4*)(Xc + (long)e1.x * 128);
                int4 r2 = *(const int4*)(Xc + (long)e2.x * 128);
                int4 r3 = *(const int4*)(Xc + (long)e3.x * 128);
                acc8(a, r0, __int_as_float(e0.y));
                acc8(a, r1, __int_as_float(e1.y));
                acc8(a, r2, __int_as_float(e2.y));
                acc8(a, r3, __int_as_float(e3.y));
            }
            for (; i < end; i += 4) {
                int2 e0 = nt_ld_int2(&ed[i]);
                int4 r0 = *(const int4*)(Xc + (long)e0.x * 128);
                acc8(a, r0, __int_as_float(e0.y));
            }
            #pragma unroll
            for (int j = 0; j < 8; ++j) {
                a[j] += __shfl_xor(a[j], 16);
                a[j] += __shfl_xor(a[j], 32);
            }
            if (g2 == 0) {
                const float dn = Dn[n];
                int4 o;
                #pragma unroll
                for (int j = 0; j < 4; ++j) {
                    unsigned lo = f2bf(a[2 * j] * dn);
                    unsigned hi = f2bf(a[2 * j + 1] * dn);
                    (&o.x)[j] = (int)((hi << 16) | lo);
                }
                *(int4*)&Xl[q * XS + 8 * l] = o;
                if (rowout) *(int4*)&rowout[(long)n * 128 + 8 * l] = o;
            }
        }
    } else {
        for (int idx = tid; idx < 64 * 16; idx += 512) {
            int r = idx >> 4;
            int c = (idx & 15) * 8;
            int n = n0 + r;
            int4 v = make_int4(0, 0, 0, 0);
            if (n < N) v = *(const int4*)(xsrc + (long)n * 128 + c);
            *(int4*)&Xl[r * XS + c] = v;
        }
    }
    __syncthreads();

    // ---- phase 2: col-split MFMA + bias + relu + LN ----
    const int wv = tid >> 6;
    const int wv2 = wv & 3;            // row-tile 0..3 (16 rows each)
    const int half = wv >> 2;          // col half 0..1 (64 cols each)
    const int ch = half * 64;
    const int rsub = lane & 15;
    const int g = lane >> 4;
    f32x4 acc[4];
    #pragma unroll
    for (int c = 0; c < 4; ++c) acc[c] = (f32x4){0.f, 0.f, 0.f, 0.f};
    const short* xbase = &Xl[(wv2 * 16 + rsub) * XS + g * 8];
    const short* wbase = &Wl[(ch + rsub) * XS + g * 8];
    #pragma unroll
    for (int kk = 0; kk < 4; ++kk) {
        bf16x8 a = *(const bf16x8*)(xbase + kk * 32);
        #pragma unroll
        for (int c = 0; c < 4; ++c) {
            bf16x8 bb = *(const bf16x8*)(wbase + c * 16 * XS + kk * 32);
            acc[c] = __builtin_amdgcn_mfma_f32_16x16x32_bf16(a, bb, acc[c], 0, 0, 0);
        }
    }
    float sum[4] = {0.f, 0.f, 0.f, 0.f};
    float ssq[4] = {0.f, 0.f, 0.f, 0.f};
    #pragma unroll
    for (int c = 0; c < 4; ++c) {
        float bias = bp[ch + c * 16 + rsub];
        #pragma unroll
        for (int r = 0; r < 4; ++r) {
            float h = acc[c][r] + bias;
            h = fmaxf(h, 0.0f);
            acc[c][r] = h;
            sum[r] += h;
            ssq[r] += h * h;
        }
    }
    #pragma unroll
    for (int msk = 1; msk < 16; msk <<= 1) {
        #pragma unroll
        for (int r = 0; r < 4; ++r) {
            sum[r] += __shfl_xor(sum[r], msk);
            ssq[r] += __shfl_xor(ssq[r], msk);
        }
    }
    if (rsub == 0) {
        #pragma unroll
        for (int r = 0; r < 4; ++r) {
            int row = wv2 * 16 + g * 4 + r;
            sums[row][half] = sum[r];
            ssqs[row][half] = ssq[r];
        }
    }
    __syncthreads();
    #pragma unroll
    for (int r = 0; r < 4; ++r) {
        int row = wv2 * 16 + g * 4 + r;
        int n = n0 + row;
        if (n >= N) continue;
        float S = sums[row][0] + sums[row][1];
        float Q = ssqs[row][0] + ssqs[row][1];
        float mean = S * (1.0f / 128.0f);
        float var = Q * (1.0f / 128.0f) - mean * mean + EPSV;
        float inv = rsqrtf(var);
        float* orow = out + (long)n * OUT_STRIDE + ocol;
        #pragma unroll
        for (int c = 0; c < 4; ++c) {
            int col = ch + c * 16 + rsub;
            __builtin_nontemporal_store((acc[c][r] - mean) * sp[col] * inv + op[col], &orow[col]);
        }
    }
}

// ---------------- fallback: push scatter + generic transform (256 threads) ----------------
__device__ __forceinline__ void stage_W(const float* __restrict__ Wf_hop, short* Wl, int tid) {
    const float4* W4 = (const float4*)Wf_hop;
    for (int idx = tid; idx < 128 * 32; idx += 256) {
        float4 v = W4[idx];
        int row = idx >> 5;
        int col = (idx & 31) * 4;
        short* p = &Wl[row * XS + col];
        p[0] = f2bf(v.x); p[1] = f2bf(v.y); p[2] = f2bf(v.z); p[3] = f2bf(v.w);
    }
}

__device__ __forceinline__ void mfma_ln_epilogue(
    const short* Xl, const short* Wl,
    const float* __restrict__ bp, const float* __restrict__ sp, const float* __restrict__ op,
    float* out, int ocol, int n0, int N, int tid)
{
    const int lane = tid & 63;
    const int wv = tid >> 6;
    f32x4 acc[8];
    #pragma unroll
    for (int c = 0; c < 8; ++c) acc[c] = (f32x4){0.f, 0.f, 0.f, 0.f};
    const int rsub = lane & 15;
    const int g = lane >> 4;
    const short* xbase = &Xl[(wv * 16 + rsub) * XS + g * 8];
    const short* wbase = &Wl[rsub * XS + g * 8];
    #pragma unroll
    for (int kk = 0; kk < 4; ++kk) {
        bf16x8 a = *(const bf16x8*)(xbase + kk * 32);
        #pragma unroll
        for (int c = 0; c < 8; ++c) {
            bf16x8 bb = *(const bf16x8*)(wbase + c * 16 * XS + kk * 32);
            acc[c] = __builtin_amdgcn_mfma_f32_16x16x32_bf16(a, bb, acc[c], 0, 0, 0);
        }
    }
    float sum[4] = {0.f, 0.f, 0.f, 0.f};
    float ssq[4] = {0.f, 0.f, 0.f, 0.f};
    #pragma unroll
    for (int c = 0; c < 8; ++c) {
        float bias = bp[c * 16 + rsub];
        #pragma unroll
        for (int r = 0; r < 4; ++r) {
            float h = acc[c][r] + bias;
            h = fmaxf(h, 0.0f);
            acc[c][r] = h;
            sum[r] += h;
            ssq[r] += h * h;
        }
    }
    #pragma unroll
    for (int msk = 1; msk < 16; msk <<= 1) {
        #pragma unroll
        for (int r = 0; r < 4; ++r) {
            sum[r] += __shfl_xor(sum[r], msk);
            ssq[r] += __shfl_xor(ssq[r], msk);
        }
    }
    #pragma unroll
    for (int r = 0; r < 4; ++r) {
        int n = n0 + wv * 16 + g * 4 + r;
        if (n >= N) continue;
        float mean = sum[r] * (1.0f / 128.0f);
        float var = ssq[r] * (1.0f / 128.0f) - mean * mean + EPSV;
        float inv = rsqrtf(var);
        float* orow = out + (long)n * OUT_STRIDE + ocol;
        #pragma unroll
        for (int c = 0; c < 8; ++c) {
            int col = c * 16 + rsub;
            orow[col] = (acc[c][r] - mean) * sp[col] * inv + op[col];
        }
    }
}

__global__ __launch_bounds__(256)
void scatter_kernel(const float* X, long xstride, long xcol0,
                    const int* __restrict__ src, const int* __restrict__ dst,
                    const float* __restrict__ w, const float* __restrict__ Dn,
                    int useDn, float* out, long ocol0, int nE)
{
    const int lane = threadIdx.x & 63;
    const int wave = (int)((blockIdx.x * blockDim.x + threadIdx.x) >> 6);
    const int nWaves = (int)((gridDim.x * blockDim.x) >> 6);
    for (int e = wave; e < nE; e += nWaves) {
        const int s = src[e];
        const int d = dst[e];
        float ww = w[e];
        if (useDn) ww *= Dn[s];
        const float2 v = *(const float2*)(X + (long)s * xstride + xcol0 + 2 * lane);
        float* o = out + (long)d * OUT_STRIDE + ocol0 + 2 * lane;
        atomicAdd(o, v.x * ww);
        atomicAdd(o + 1, v.y * ww);
    }
}

__global__ __launch_bounds__(256)
void transform_f32_kernel(const float* x, long xs, int useDnIn,
                          const float* __restrict__ Dn,
                          const float* __restrict__ Wf_hop,
                          const float* __restrict__ bp, const float* __restrict__ sp,
                          const float* __restrict__ op,
                          float* out, int ocol, int N)
{
    __shared__ __attribute__((aligned(16))) short Wl[128 * XS];
    __shared__ __attribute__((aligned(16))) short Xl[64 * XS];
    const int tid = threadIdx.x;
    stage_W(Wf_hop, Wl, tid);
    const int n0 = blockIdx.x * 64;
    for (int idx = tid; idx < 64 * 32; idx += 256) {
        int r = idx >> 5;
        int col = (idx & 31) * 4;
        int n = n0 + r;
        float4 v = make_float4(0.f, 0.f, 0.f, 0.f);
        float m = 1.0f;
        if (n < N) {
            v = *(const float4*)(x + (long)n * xs + col);
            if (useDnIn) m = Dn[n];
        }
        short* p = &Xl[r * XS + col];
        p[0] = f2bf(v.x * m); p[1] = f2bf(v.y * m); p[2] = f2bf(v.z * m); p[3] = f2bf(v.w * m);
    }
    __syncthreads();
    mfma_ln_epilogue(Xl, Wl, bp, sp, op, out, ocol, n0, N, tid);
}

extern "C" void kernel_launch(void* const* d_in, const int* in_sizes, int n_in,
                              void* d_out, int out_size, void* d_ws, size_t ws_size,
                              hipStream_t stream) {
    const float* features = (const float*)d_in[0];
    const int*   src      = (const int*)d_in[1];
    const int*   dst      = (const int*)d_in[2];
    const float* w        = (const float*)d_in[3];
    const float* Dn       = (const float*)d_in[4];
    const float* W        = (const float*)d_in[5];
    const float* b        = (const float*)d_in[6];
    const float* scale    = (const float*)d_in[7];
    const float* offset   = (const float*)d_in[8];
    float* out = (float*)d_out;
    const int N = in_sizes[0] / 128;
    const int E = in_sizes[1];
    const int NB = (N + BS - 1) >> BSH;
    const int nblk = (N + 63) / 64;
    int CAP = ((E / (NB > 0 ? NB : 1)) * 3 / 2 + 255) & ~255;
    if (CAP < 1024) CAP = 1024;
    const size_t NC = (size_t)NB * CAP;

    // ws layout (ints): off[N] deg[N] | ed[2NC] | bcur[NB] | edw[2NC] | dlu[NC/2] | featb[64N] h1b[64N]
    const size_t o_off = 0;
    const size_t o_deg = (size_t)N;
    const size_t o_ed  = ((size_t)2 * N + 3) & ~(size_t)3;
    const size_t o_bc  = o_ed + 2 * NC;
    const size_t o_un  = (o_bc + NB + 3) & ~(size_t)3;
    const size_t o_dl  = o_un + 2 * NC;
    const size_t o_fb  = (o_dl + (NC + 1) / 2 + 3) & ~(size_t)3;
    const size_t need  = (o_fb + 2 * (size_t)64 * N) * 4;

    if (NB <= NBMAX && ws_size >= need) {
        int* ws_i  = (int*)d_ws;
        int* off   = ws_i + o_off;
        int* deg   = ws_i + o_deg;
        int2* ed   = (int2*)(ws_i + o_ed);
        int* bcur  = ws_i + o_bc;
        int2* edw  = (int2*)(ws_i + o_un);
        unsigned short* dlu = (unsigned short*)(ws_i + o_dl);
        unsigned short* featb = (unsigned short*)(ws_i + o_fb);
        unsigned short* h1b   = featb + (size_t)N * 128;

        hipMemsetAsync(bcur, 0, (size_t)NB * 4, stream);
        multisplit_pack_kernel<<<(E + CH - 1) / CH, 256, 0, stream>>>(
            src, dst, w, bcur, edw, dlu, E, CAP, features, featb, (long)N * 32);
        bucket_csr_kernel<<<NB, 256, 0, stream>>>(edw, dlu, bcur, off, deg, ed, N, CAP);

        // hop 1: gather featb -> h1b + transform -> out[:,128:256)
        fusedT_kernel<<<nblk, 512, 0, stream>>>(featb, off, deg, ed, Dn,
            W + 128 * 128, b + 128, scale + 128, offset + 128, h1b, out, 128, N, 1);
        // hop 2: gather h1b -> LDS only + transform -> out[:,256:384)
        fusedT_kernel<<<nblk, 512, 0, stream>>>(h1b, off, deg, ed, Dn,
            W + 2 * 128 * 128, b + 256, scale + 256, offset + 256, nullptr, out, 256, N, 1);
        // hop 0: stage featb + transform -> out[:,0:128)
        fusedT_kernel<<<nblk, 512, 0, stream>>>(featb, off, deg, ed, Dn,
            W, b, scale, offset, nullptr, out, 0, N, 0);
    } else {
        // fallback: atomic scatter path (raw agg stored; Dn applied on read)
        hipMemsetAsync(out, 0, (size_t)out_size * sizeof(float), stream);
        scatter_kernel<<<2048, 256, 0, stream>>>(features, 128, 0, src, dst, w, Dn, 0, out, 128, E);
        scatter_kernel<<<2048, 256, 0, stream>>>(out, OUT_STRIDE, 128, src, dst, w, Dn, 1, out, 256, E);
        transform_f32_kernel<<<nblk, 256, 0, stream>>>(features, 128, 0, Dn, W, b, scale, offset, out, 0, N);
        transform_f32_kernel<<<nblk, 256, 0, stream>>>(out + 128, OUT_STRIDE, 1, Dn, W + 128 * 128, b + 128, scale + 128, offset + 128, out, 128, N);
        transform_f32_kernel<<<nblk, 256, 0, stream>>>(out + 256, OUT_STRIDE, 1, Dn, W + 2 * 128 * 128, b + 256, scale + 256, offset + 256, out, 256, N);
    }
}

// Round 13
// 322.446 us; speedup vs baseline: 1.0926x; 1.0926x over previous
//
#include <hip/hip_runtime.h>
#include <hip/hip_bf16.h>

#define OUT_STRIDE 384
#define EPSV 1e-9f
#define BSH 9
#define BS 512             // nodes per bucket
#define NBMAX 512
#define CH 4096            // edges per multisplit chunk
#define XS 136

typedef __attribute__((ext_vector_type(8))) short bf16x8;
typedef __attribute__((ext_vector_type(4))) float f32x4;

static __device__ __forceinline__ unsigned short f2bf(float f) {
    __hip_bfloat16 h = __float2bfloat16(f);
    return *reinterpret_cast<unsigned short*>(&h);
}

// ---------------- multisplit (fixed-capacity buckets) + feature pack ----------------
__global__ __launch_bounds__(256)
void multisplit_pack_kernel(const int* __restrict__ src, const int* __restrict__ dst,
                            const float* __restrict__ w, int* __restrict__ bcur,
                            int2* __restrict__ edw, unsigned short* __restrict__ dlu,
                            int E, int CAP,
                            const float* __restrict__ features,
                            unsigned short* __restrict__ featb, long n4) {
    __shared__ int hist[NBMAX], scan_[NBMAX], gbase[NBMAX], lcur[NBMAX];
    __shared__ int recS[CH * 3];
    __shared__ int wt[4];
    const int t = threadIdx.x;
    const int lane = t & 63, wv = t >> 6;
    const int c0 = blockIdx.x * CH;
    const int cnt_total = min(CH, E - c0);

    int d_reg[CH / 256];               // register-cached dst values (one L2 read only)
    for (int i = t; i < NBMAX; i += 256) hist[i] = 0;
    __syncthreads();
    #pragma unroll
    for (int p = 0; p < CH / 256; ++p) {
        int i = c0 + p * 256 + t;
        d_reg[p] = (i < E) ? dst[i] : -1;
        if (i < E) atomicAdd(&hist[d_reg[p] >> BSH], 1);
    }
    __syncthreads();
    {   // exclusive scan of hist[0..NBMAX)
        int b0 = 2 * t, b1 = 2 * t + 1;
        int h0 = hist[b0], h1 = hist[b1];
        int s = h0 + h1;
        int inc = s;
        #pragma unroll
        for (int d = 1; d < 64; d <<= 1) { int u = __shfl_up(inc, d); if (lane >= d) inc += u; }
        if (lane == 63) wt[wv] = inc;
        __syncthreads();
        int base = 0;
        for (int w2 = 0; w2 < wv; ++w2) base += wt[w2];
        int ex = base + inc - s;
        scan_[b0] = ex;
        scan_[b1] = ex + h0;
    }
    __syncthreads();
    for (int i = t; i < NBMAX; i += 256) {
        if (hist[i] > 0) gbase[i] = atomicAdd(&bcur[i], hist[i]);
        lcur[i] = scan_[i];
    }
    __syncthreads();
    #pragma unroll
    for (int p = 0; p < CH / 256; ++p) {
        int i = c0 + p * 256 + t;
        if (i < E) {
            int d = d_reg[p];
            int b = d >> BSH;
            int j = atomicAdd(&lcur[b], 1);
            recS[3 * j]     = src[i];
            recS[3 * j + 1] = d;
            recS[3 * j + 2] = __float_as_int(w[i]);
        }
    }
    __syncthreads();
    #pragma unroll
    for (int p = 0; p < CH / 256; ++p) {
        int j = p * 256 + t;
        if (j < cnt_total) {
            int d = recS[3 * j + 1];
            int b = d >> BSH;
            int g = gbase[b] + (j - scan_[b]);
            if (g < CAP) {                         // overflow clamp (deterministic)
                long gp = (long)b * CAP + g;
                edw[gp] = make_int2(recS[3 * j], recS[3 * j + 2]);
                dlu[gp] = (unsigned short)(d - (b << BSH));
            }
        }
    }
    // independent stream: pack features f32 -> bf16
    long gid = blockIdx.x * blockDim.x + threadIdx.x;
    long stride = (long)gridDim.x * blockDim.x;
    for (long p = gid; p < n4; p += stride) {
        float4 v = ((const float4*)features)[p];
        ushort4 o;
        o.x = f2bf(v.x); o.y = f2bf(v.y); o.z = f2bf(v.z); o.w = f2bf(v.w);
        *(ushort4*)&featb[p * 4] = o;
    }
}

// ---------------- per-bucket CSR build (LDS cursors) ----------------
__global__ __launch_bounds__(256)
void bucket_csr_kernel(const int2* __restrict__ edw, const unsigned short* __restrict__ dlu,
                       const int* __restrict__ bcur,
                       int* __restrict__ off, int* __restrict__ deg,
                       int2* __restrict__ ed, int N, int CAP) {
    __shared__ int h[BS];
    __shared__ int wt[4];
    const int b = blockIdx.x;
    const int t = threadIdx.x;
    const int lane = t & 63, wv = t >> 6;
    const int cnt = min(bcur[b], CAP);
    const long base = (long)b * CAP;
    const int n0 = b << BSH;
    const int nn = min(BS, N - n0);

    for (int i = t; i < BS; i += 256) h[i] = 0;
    __syncthreads();
    for (int i = t; i < cnt; i += 256) atomicAdd(&h[dlu[base + i]], 1);
    __syncthreads();
    {
        int j0 = 2 * t;
        int l0 = h[j0], l1 = h[j0 + 1];
        int s = l0 + l1;
        int inc = s;
        #pragma unroll
        for (int d = 1; d < 64; d <<= 1) { int u = __shfl_up(inc, d); if (lane >= d) inc += u; }
        if (lane == 63) wt[wv] = inc;
        __syncthreads();
        int base_ = 0;
        for (int w2 = 0; w2 < wv; ++w2) base_ += wt[w2];
        int ex = base_ + inc - s;
        int e0 = ex, e1 = ex + l0;
        __syncthreads();
        h[j0] = e0; h[j0 + 1] = e1;
        if (j0 < nn)     { off[n0 + j0]     = (int)(base + e0); deg[n0 + j0]     = l0; }
        if (j0 + 1 < nn) { off[n0 + j0 + 1] = (int)(base + e1); deg[n0 + j0 + 1] = l1; }
    }
    __syncthreads();
    for (int i = t; i < cnt; i += 256) {
        int d = dlu[base + i];
        int pos = atomicAdd(&h[d], 1);
        ed[base + pos] = edw[base + i];
    }
}

// ---------------- gather: one wave per node, 4-way split, 4-wide unroll ----------------
__device__ __forceinline__ void acc8(float* a, int4 r, float w) {
    #pragma unroll
    for (int j = 0; j < 4; ++j) {
        int bits = (&r.x)[j];
        float f0 = __int_as_float(bits << 16);
        float f1 = __int_as_float(bits & 0xffff0000);
        a[2 * j]     += f0 * w;
        a[2 * j + 1] += f1 * w;
    }
}

__device__ __forceinline__ int2 nt_ld_int2(const int2* p) {
    long v = __builtin_nontemporal_load((const long*)p);
    int2 r; r.x = (int)(v & 0xffffffffL); r.y = (int)(((unsigned long)v) >> 32);
    return r;
}

__global__ __launch_bounds__(256)
void gather_wave(const unsigned short* __restrict__ X,
                 const int* __restrict__ off, const int* __restrict__ deg,
                 const int2* __restrict__ ed,
                 const float* __restrict__ Dn,
                 unsigned short* __restrict__ outb, int N) {
    const int tid = threadIdx.x;
    const int n = blockIdx.x * 4 + (tid >> 6);    // one wave per node
    if (n >= N) return;
    const int lane = tid & 63;
    const int g2 = lane >> 4;                     // 0..3 edge-split group
    const int l = lane & 15;                      // 16 lanes x 16B = 256B row
    const int beg = __builtin_nontemporal_load(&off[n]);
    const int end = beg + __builtin_nontemporal_load(&deg[n]);
    float a[8] = {0.f, 0.f, 0.f, 0.f, 0.f, 0.f, 0.f, 0.f};
    const unsigned short* Xc = X + 8 * l;
    int i = beg + g2;
    for (; i + 12 < end; i += 16) {               // 4 edges per group in flight
        int2 e0 = nt_ld_int2(&ed[i]);
        int2 e1 = nt_ld_int2(&ed[i + 4]);
        int2 e2 = nt_ld_int2(&ed[i + 8]);
        int2 e3 = nt_ld_int2(&ed[i + 12]);
        int4 r0 = *(const int4*)(Xc + (long)e0.x * 128);
        int4 r1 = *(const int4*)(Xc + (long)e1.x * 128);
        int4 r2 = *(const int4*)(Xc + (long)e2.x * 128);
        int4 r3 = *(const int4*)(Xc + (long)e3.x * 128);
        acc8(a, r0, __int_as_float(e0.y));
        acc8(a, r1, __int_as_float(e1.y));
        acc8(a, r2, __int_as_float(e2.y));
        acc8(a, r3, __int_as_float(e3.y));
    }
    for (; i < end; i += 4) {
        int2 e0 = nt_ld_int2(&ed[i]);
        int4 r0 = *(const int4*)(Xc + (long)e0.x * 128);
        acc8(a, r0, __int_as_float(e0.y));
    }
    #pragma unroll
    for (int j = 0; j < 8; ++j) {
        a[j] += __shfl_xor(a[j], 16);
        a[j] += __shfl_xor(a[j], 32);
    }
    if (g2 == 0) {
        const float dn = Dn[n];
        int4 o;
        #pragma unroll
        for (int j = 0; j < 4; ++j) {
            unsigned lo = f2bf(a[2 * j] * dn);
            unsigned hi = f2bf(a[2 * j + 1] * dn);
            (&o.x)[j] = (int)((hi << 16) | lo);
        }
        *(int4*)&outb[(long)n * 128 + 8 * l] = o;
    }
}

// ---------------- shared MFMA + LN epilogue ----------------
__device__ __forceinline__ void stage_W(const float* __restrict__ Wf_hop, short* Wl, int tid) {
    const float4* W4 = (const float4*)Wf_hop;
    for (int idx = tid; idx < 128 * 32; idx += 256) {
        float4 v = W4[idx];
        int row = idx >> 5;
        int col = (idx & 31) * 4;
        short* p = &Wl[row * XS + col];
        p[0] = f2bf(v.x); p[1] = f2bf(v.y); p[2] = f2bf(v.z); p[3] = f2bf(v.w);
    }
}

__device__ __forceinline__ void mfma_ln_epilogue(
    const short* Xl, const short* Wl,
    const float* __restrict__ bp, const float* __restrict__ sp, const float* __restrict__ op,
    float* out, int ocol, int n0, int N, int tid)
{
    const int lane = tid & 63;
    const int wv = tid >> 6;
    f32x4 acc[8];
    #pragma unroll
    for (int c = 0; c < 8; ++c) acc[c] = (f32x4){0.f, 0.f, 0.f, 0.f};
    const int rsub = lane & 15;
    const int g = lane >> 4;
    const short* xbase = &Xl[(wv * 16 + rsub) * XS + g * 8];
    const short* wbase = &Wl[rsub * XS + g * 8];
    #pragma unroll
    for (int kk = 0; kk < 4; ++kk) {
        bf16x8 a = *(const bf16x8*)(xbase + kk * 32);
        #pragma unroll
        for (int c = 0; c < 8; ++c) {
            bf16x8 bb = *(const bf16x8*)(wbase + c * 16 * XS + kk * 32);
            acc[c] = __builtin_amdgcn_mfma_f32_16x16x32_bf16(a, bb, acc[c], 0, 0, 0);
        }
    }
    float sum[4] = {0.f, 0.f, 0.f, 0.f};
    float ssq[4] = {0.f, 0.f, 0.f, 0.f};
    #pragma unroll
    for (int c = 0; c < 8; ++c) {
        float bias = bp[c * 16 + rsub];
        #pragma unroll
        for (int r = 0; r < 4; ++r) {
            float h = acc[c][r] + bias;
            h = fmaxf(h, 0.0f);
            acc[c][r] = h;
            sum[r] += h;
            ssq[r] += h * h;
        }
    }
    #pragma unroll
    for (int msk = 1; msk < 16; msk <<= 1) {
        #pragma unroll
        for (int r = 0; r < 4; ++r) {
            sum[r] += __shfl_xor(sum[r], msk);
            ssq[r] += __shfl_xor(ssq[r], msk);
        }
    }
    #pragma unroll
    for (int r = 0; r < 4; ++r) {
        int n = n0 + wv * 16 + g * 4 + r;
        if (n >= N) continue;
        float mean = sum[r] * (1.0f / 128.0f);
        float var = ssq[r] * (1.0f / 128.0f) - mean * mean + EPSV;
        float inv = rsqrtf(var);
        float* orow = out + (long)n * OUT_STRIDE + ocol;
        #pragma unroll
        for (int c = 0; c < 8; ++c) {
            int col = c * 16 + rsub;
            __builtin_nontemporal_store((acc[c][r] - mean) * sp[col] * inv + op[col], &orow[col]);
        }
    }
}

// ---------------- transform: all 3 hops from bf16 rows, 4 row-tiles per block ----------------
__global__ __launch_bounds__(256)
void transform3_kernel(const unsigned short* __restrict__ featb,
                       const unsigned short* __restrict__ h1b,
                       const unsigned short* __restrict__ h2b,
                       const float* __restrict__ Wf,
                       const float* __restrict__ bf, const float* __restrict__ scf,
                       const float* __restrict__ offp,
                       float* out, int N)
{
    const int hop = blockIdx.y;
    const int tid = threadIdx.x;
    __shared__ __attribute__((aligned(16))) short Wl[128 * XS];
    __shared__ __attribute__((aligned(16))) short Xl[64 * XS];
    stage_W(Wf + (long)hop * 128 * 128, Wl, tid);
    const unsigned short* xb = (hop == 0) ? featb : (hop == 1) ? h1b : h2b;
    #pragma unroll
    for (int t2 = 0; t2 < 4; ++t2) {
        const int n0 = (blockIdx.x * 4 + t2) * 64;
        if (n0 >= N) break;
        for (int idx = tid; idx < 64 * 16; idx += 256) {
            int r = idx >> 4;
            int c = (idx & 15) * 8;
            int n = n0 + r;
            int4 v = make_int4(0, 0, 0, 0);
            if (n < N) {
                const int4* p = (const int4*)(xb + (long)n * 128 + c);
                v.x = __builtin_nontemporal_load(&p->x);
                v.y = __builtin_nontemporal_load(&p->y);
                v.z = __builtin_nontemporal_load(&p->z);
                v.w = __builtin_nontemporal_load(&p->w);
            }
            *(int4*)&Xl[r * XS + c] = v;
        }
        __syncthreads();
        mfma_ln_epilogue(Xl, Wl, bf + hop * 128, scf + hop * 128, offp + hop * 128,
                         out, hop * 128, n0, N, tid);
        __syncthreads();
    }
}

// ---------------- fallback: push scatter + generic transform ----------------
__global__ __launch_bounds__(256)
void scatter_kernel(const float* X, long xstride, long xcol0,
                    const int* __restrict__ src, const int* __restrict__ dst,
                    const float* __restrict__ w, const float* __restrict__ Dn,
                    int useDn, float* out, long ocol0, int nE)
{
    const int lane = threadIdx.x & 63;
    const int wave = (int)((blockIdx.x * blockDim.x + threadIdx.x) >> 6);
    const int nWaves = (int)((gridDim.x * blockDim.x) >> 6);
    for (int e = wave; e < nE; e += nWaves) {
        const int s = src[e];
        const int d = dst[e];
        float ww = w[e];
        if (useDn) ww *= Dn[s];
        const float2 v = *(const float2*)(X + (long)s * xstride + xcol0 + 2 * lane);
        float* o = out + (long)d * OUT_STRIDE + ocol0 + 2 * lane;
        atomicAdd(o, v.x * ww);
        atomicAdd(o + 1, v.y * ww);
    }
}

__global__ __launch_bounds__(256)
void transform_f32_kernel(const float* x, long xs, int useDnIn,
                          const float* __restrict__ Dn,
                          const float* __restrict__ Wf_hop,
                          const float* __restrict__ bp, const float* __restrict__ sp,
                          const float* __restrict__ op,
                          float* out, int ocol, int N)
{
    __shared__ __attribute__((aligned(16))) short Wl[128 * XS];
    __shared__ __attribute__((aligned(16))) short Xl[64 * XS];
    const int tid = threadIdx.x;
    stage_W(Wf_hop, Wl, tid);
    const int n0 = blockIdx.x * 64;
    for (int idx = tid; idx < 64 * 32; idx += 256) {
        int r = idx >> 5;
        int col = (idx & 31) * 4;
        int n = n0 + r;
        float4 v = make_float4(0.f, 0.f, 0.f, 0.f);
        float m = 1.0f;
        if (n < N) {
            v = *(const float4*)(x + (long)n * xs + col);
            if (useDnIn) m = Dn[n];
        }
        short* p = &Xl[r * XS + col];
        p[0] = f2bf(v.x * m); p[1] = f2bf(v.y * m); p[2] = f2bf(v.z * m); p[3] = f2bf(v.w * m);
    }
    __syncthreads();
    mfma_ln_epilogue(Xl, Wl, bp, sp, op, out, ocol, n0, N, tid);
}

extern "C" void kernel_launch(void* const* d_in, const int* in_sizes, int n_in,
                              void* d_out, int out_size, void* d_ws, size_t ws_size,
                              hipStream_t stream) {
    const float* features = (const float*)d_in[0];
    const int*   src      = (const int*)d_in[1];
    const int*   dst      = (const int*)d_in[2];
    const float* w        = (const float*)d_in[3];
    const float* Dn       = (const float*)d_in[4];
    const float* W        = (const float*)d_in[5];
    const float* b        = (const float*)d_in[6];
    const float* scale    = (const float*)d_in[7];
    const float* offset   = (const float*)d_in[8];
    float* out = (float*)d_out;
    const int N = in_sizes[0] / 128;
    const int E = in_sizes[1];
    const int NB = (N + BS - 1) >> BSH;
    const int nblk = (N + 63) / 64;
    int CAP = ((E / (NB > 0 ? NB : 1)) * 3 / 2 + 255) & ~255;
    if (CAP < 1024) CAP = 1024;
    const size_t NC = (size_t)NB * CAP;

    // ws layout (ints): off[N] deg[N] | ed[2NC] | bcur[NB] | edw[2NC] | dlu[NC/2] | featb[64N] h1b[64N] h2b[64N]
    const size_t o_off = 0;
    const size_t o_deg = (size_t)N;
    const size_t o_ed  = ((size_t)2 * N + 3) & ~(size_t)3;
    const size_t o_bc  = o_ed + 2 * NC;
    const size_t o_un  = (o_bc + NB + 3) & ~(size_t)3;
    const size_t o_dl  = o_un + 2 * NC;
    const size_t o_fb  = (o_dl + (NC + 1) / 2 + 3) & ~(size_t)3;
    const size_t need  = (o_fb + 3 * (size_t)64 * N) * 4;

    if (NB <= NBMAX && ws_size >= need) {
        int* ws_i  = (int*)d_ws;
        int* off   = ws_i + o_off;
        int* deg   = ws_i + o_deg;
        int2* ed   = (int2*)(ws_i + o_ed);
        int* bcur  = ws_i + o_bc;
        int2* edw  = (int2*)(ws_i + o_un);
        unsigned short* dlu = (unsigned short*)(ws_i + o_dl);
        unsigned short* featb = (unsigned short*)(ws_i + o_fb);
        unsigned short* h1b   = featb + (size_t)N * 128;
        unsigned short* h2b   = h1b + (size_t)N * 128;

        hipMemsetAsync(bcur, 0, (size_t)NB * 4, stream);
        multisplit_pack_kernel<<<(E + CH - 1) / CH, 256, 0, stream>>>(
            src, dst, w, bcur, edw, dlu, E, CAP, features, featb, (long)N * 32);
        bucket_csr_kernel<<<NB, 256, 0, stream>>>(edw, dlu, bcur, off, deg, ed, N, CAP);

        gather_wave<<<(N + 3) / 4, 256, 0, stream>>>(featb, off, deg, ed, Dn, h1b, N);
        gather_wave<<<(N + 3) / 4, 256, 0, stream>>>(h1b, off, deg, ed, Dn, h2b, N);

        dim3 tg((N + 255) / 256, 3);
        transform3_kernel<<<tg, 256, 0, stream>>>(featb, h1b, h2b, W, b, scale, offset, out, N);
    } else {
        // fallback: atomic scatter path (raw agg stored; Dn applied on read)
        hipMemsetAsync(out, 0, (size_t)out_size * sizeof(float), stream);
        scatter_kernel<<<2048, 256, 0, stream>>>(features, 128, 0, src, dst, w, Dn, 0, out, 128, E);
        scatter_kernel<<<2048, 256, 0, stream>>>(out, OUT_STRIDE, 128, src, dst, w, Dn, 1, out, 256, E);
        transform_f32_kernel<<<nblk, 256, 0, stream>>>(features, 128, 0, Dn, W, b, scale, offset, out, 0, N);
        transform_f32_kernel<<<nblk, 256, 0, stream>>>(out + 128, OUT_STRIDE, 1, Dn, W + 128 * 128, b + 128, scale + 128, offset + 128, out, 128, N);
        transform_f32_kernel<<<nblk, 256, 0, stream>>>(out + 256, OUT_STRIDE, 1, Dn, W + 2 * 128 * 128, b + 256, scale + 256, offset + 256, out, 256, N);
    }
}

// Round 14
// 306.385 us; speedup vs baseline: 1.1498x; 1.0524x over previous
//
#include <hip/hip_runtime.h>
#include <hip/hip_bf16.h>

#define OUT_STRIDE 384
#define EPSV 1e-9f
#define BSH 9
#define BS 512             // nodes per bucket
#define NBMAX 512
#define CH 4096            // edges per multisplit chunk
#define XS 136

typedef __attribute__((ext_vector_type(8))) short bf16x8;
typedef __attribute__((ext_vector_type(4))) float f32x4;

static __device__ __forceinline__ unsigned short f2bf(float f) {
    __hip_bfloat16 h = __float2bfloat16(f);
    return *reinterpret_cast<unsigned short*>(&h);
}

// ---------------- multisplit (fixed-capacity buckets) + feature pack ----------------
__global__ __launch_bounds__(256)
void multisplit_pack_kernel(const int* __restrict__ src, const int* __restrict__ dst,
                            const float* __restrict__ w, int* __restrict__ bcur,
                            int2* __restrict__ edw, unsigned short* __restrict__ dlu,
                            int E, int CAP,
                            const float* __restrict__ features,
                            unsigned short* __restrict__ featb, long n4) {
    __shared__ int hist[NBMAX], scan_[NBMAX], gbase[NBMAX], lcur[NBMAX];
    __shared__ int recS[CH * 3];
    __shared__ int wt[4];
    const int t = threadIdx.x;
    const int lane = t & 63, wv = t >> 6;
    const int c0 = blockIdx.x * CH;
    const int cnt_total = min(CH, E - c0);

    for (int i = t; i < NBMAX; i += 256) hist[i] = 0;
    __syncthreads();
    #pragma unroll
    for (int p = 0; p < CH / 256; ++p) {
        int i = c0 + p * 256 + t;
        if (i < E) atomicAdd(&hist[dst[i] >> BSH], 1);
    }
    __syncthreads();
    {   // exclusive scan of hist[0..NBMAX)
        int b0 = 2 * t, b1 = 2 * t + 1;
        int h0 = hist[b0], h1 = hist[b1];
        int s = h0 + h1;
        int inc = s;
        #pragma unroll
        for (int d = 1; d < 64; d <<= 1) { int u = __shfl_up(inc, d); if (lane >= d) inc += u; }
        if (lane == 63) wt[wv] = inc;
        __syncthreads();
        int base = 0;
        for (int w2 = 0; w2 < wv; ++w2) base += wt[w2];
        int ex = base + inc - s;
        scan_[b0] = ex;
        scan_[b1] = ex + h0;
    }
    __syncthreads();
    for (int i = t; i < NBMAX; i += 256) {
        if (hist[i] > 0) gbase[i] = atomicAdd(&bcur[i], hist[i]);
        lcur[i] = scan_[i];
    }
    __syncthreads();
    #pragma unroll
    for (int p = 0; p < CH / 256; ++p) {
        int i = c0 + p * 256 + t;
        if (i < E) {
            int d = dst[i];
            int b = d >> BSH;
            int j = atomicAdd(&lcur[b], 1);
            recS[3 * j]     = src[i];
            recS[3 * j + 1] = d;
            recS[3 * j + 2] = __float_as_int(w[i]);
        }
    }
    __syncthreads();
    #pragma unroll
    for (int p = 0; p < CH / 256; ++p) {
        int j = p * 256 + t;
        if (j < cnt_total) {
            int d = recS[3 * j + 1];
            int b = d >> BSH;
            int g = gbase[b] + (j - scan_[b]);
            if (g < CAP) {                         // overflow clamp (deterministic)
                long gp = (long)b * CAP + g;
                edw[gp] = make_int2(recS[3 * j], recS[3 * j + 2]);
                dlu[gp] = (unsigned short)(d - (b << BSH));
            }
        }
    }
    // independent stream: pack features f32 -> bf16
    long gid = blockIdx.x * blockDim.x + threadIdx.x;
    long stride = (long)gridDim.x * blockDim.x;
    for (long p = gid; p < n4; p += stride) {
        float4 v = ((const float4*)features)[p];
        ushort4 o;
        o.x = f2bf(v.x); o.y = f2bf(v.y); o.z = f2bf(v.z); o.w = f2bf(v.w);
        *(ushort4*)&featb[p * 4] = o;
    }
}

// ---------------- per-bucket CSR build (LDS cursors) ----------------
__global__ __launch_bounds__(256)
void bucket_csr_kernel(const int2* __restrict__ edw, const unsigned short* __restrict__ dlu,
                       const int* __restrict__ bcur,
                       int* __restrict__ off, int* __restrict__ deg,
                       int2* __restrict__ ed, int N, int CAP) {
    __shared__ int h[BS];
    __shared__ int wt[4];
    const int b = blockIdx.x;
    const int t = threadIdx.x;
    const int lane = t & 63, wv = t >> 6;
    const int cnt = min(bcur[b], CAP);
    const long base = (long)b * CAP;
    const int n0 = b << BSH;
    const int nn = min(BS, N - n0);

    for (int i = t; i < BS; i += 256) h[i] = 0;
    __syncthreads();
    for (int i = t; i < cnt; i += 256) atomicAdd(&h[dlu[base + i]], 1);
    __syncthreads();
    {
        int j0 = 2 * t;
        int l0 = h[j0], l1 = h[j0 + 1];
        int s = l0 + l1;
        int inc = s;
        #pragma unroll
        for (int d = 1; d < 64; d <<= 1) { int u = __shfl_up(inc, d); if (lane >= d) inc += u; }
        if (lane == 63) wt[wv] = inc;
        __syncthreads();
        int base_ = 0;
        for (int w2 = 0; w2 < wv; ++w2) base_ += wt[w2];
        int ex = base_ + inc - s;
        int e0 = ex, e1 = ex + l0;
        __syncthreads();
        h[j0] = e0; h[j0 + 1] = e1;
        if (j0 < nn)     { off[n0 + j0]     = (int)(base + e0); deg[n0 + j0]     = l0; }
        if (j0 + 1 < nn) { off[n0 + j0 + 1] = (int)(base + e1); deg[n0 + j0 + 1] = l1; }
    }
    __syncthreads();
    for (int i = t; i < cnt; i += 256) {
        int d = dlu[base + i];
        int pos = atomicAdd(&h[d], 1);
        ed[base + pos] = edw[base + i];
    }
}

// ---------------- gather: one wave per node, 4-way split, 4-wide unroll ----------------
// ed/off/deg are single-use cold streams -> nontemporal loads keep L2 for the row table X.
__device__ __forceinline__ void acc8(float* a, int4 r, float w) {
    #pragma unroll
    for (int j = 0; j < 4; ++j) {
        int bits = (&r.x)[j];
        float f0 = __int_as_float(bits << 16);
        float f1 = __int_as_float(bits & 0xffff0000);
        a[2 * j]     += f0 * w;
        a[2 * j + 1] += f1 * w;
    }
}

__device__ __forceinline__ int2 nt_ld_int2(const int2* p) {
    long v = __builtin_nontemporal_load((const long*)p);
    int2 r; r.x = (int)(v & 0xffffffffL); r.y = (int)(((unsigned long)v) >> 32);
    return r;
}

__global__ __launch_bounds__(256)
void gather_wave(const unsigned short* __restrict__ X,
                 const int* __restrict__ off, const int* __restrict__ deg,
                 const int2* __restrict__ ed,
                 const float* __restrict__ Dn,
                 unsigned short* __restrict__ outb, int N) {
    const int tid = threadIdx.x;
    const int n = blockIdx.x * 4 + (tid >> 6);    // one wave per node
    if (n >= N) return;
    const int lane = tid & 63;
    const int g2 = lane >> 4;                     // 0..3 edge-split group
    const int l = lane & 15;                      // 16 lanes x 16B = 256B row
    const int beg = __builtin_nontemporal_load(&off[n]);
    const int end = beg + __builtin_nontemporal_load(&deg[n]);
    float a[8] = {0.f, 0.f, 0.f, 0.f, 0.f, 0.f, 0.f, 0.f};
    const unsigned short* Xc = X + 8 * l;
    int i = beg + g2;
    for (; i + 12 < end; i += 16) {               // 4 edges per group in flight
        int2 e0 = nt_ld_int2(&ed[i]);
        int2 e1 = nt_ld_int2(&ed[i + 4]);
        int2 e2 = nt_ld_int2(&ed[i + 8]);
        int2 e3 = nt_ld_int2(&ed[i + 12]);
        int4 r0 = *(const int4*)(Xc + (long)e0.x * 128);
        int4 r1 = *(const int4*)(Xc + (long)e1.x * 128);
        int4 r2 = *(const int4*)(Xc + (long)e2.x * 128);
        int4 r3 = *(const int4*)(Xc + (long)e3.x * 128);
        acc8(a, r0, __int_as_float(e0.y));
        acc8(a, r1, __int_as_float(e1.y));
        acc8(a, r2, __int_as_float(e2.y));
        acc8(a, r3, __int_as_float(e3.y));
    }
    for (; i < end; i += 4) {
        int2 e0 = nt_ld_int2(&ed[i]);
        int4 r0 = *(const int4*)(Xc + (long)e0.x * 128);
        acc8(a, r0, __int_as_float(e0.y));
    }
    #pragma unroll
    for (int j = 0; j < 8; ++j) {
        a[j] += __shfl_xor(a[j], 16);
        a[j] += __shfl_xor(a[j], 32);
    }
    if (g2 == 0) {
        const float dn = Dn[n];
        int4 o;
        #pragma unroll
        for (int j = 0; j < 4; ++j) {
            unsigned lo = f2bf(a[2 * j] * dn);
            unsigned hi = f2bf(a[2 * j + 1] * dn);
            (&o.x)[j] = (int)((hi << 16) | lo);
        }
        *(int4*)&outb[(long)n * 128 + 8 * l] = o;
    }
}

// ---------------- shared MFMA + LN epilogue ----------------
__device__ __forceinline__ void stage_W(const float* __restrict__ Wf_hop, short* Wl, int tid) {
    const float4* W4 = (const float4*)Wf_hop;
    for (int idx = tid; idx < 128 * 32; idx += 256) {
        float4 v = W4[idx];
        int row = idx >> 5;
        int col = (idx & 31) * 4;
        short* p = &Wl[row * XS + col];
        p[0] = f2bf(v.x); p[1] = f2bf(v.y); p[2] = f2bf(v.z); p[3] = f2bf(v.w);
    }
}

__device__ __forceinline__ void mfma_ln_epilogue(
    const short* Xl, const short* Wl,
    const float* __restrict__ bp, const float* __restrict__ sp, const float* __restrict__ op,
    float* out, int ocol, int n0, int N, int tid)
{
    const int lane = tid & 63;
    const int wv = tid >> 6;
    f32x4 acc[8];
    #pragma unroll
    for (int c = 0; c < 8; ++c) acc[c] = (f32x4){0.f, 0.f, 0.f, 0.f};
    const int rsub = lane & 15;
    const int g = lane >> 4;
    const short* xbase = &Xl[(wv * 16 + rsub) * XS + g * 8];
    const short* wbase = &Wl[rsub * XS + g * 8];
    #pragma unroll
    for (int kk = 0; kk < 4; ++kk) {
        bf16x8 a = *(const bf16x8*)(xbase + kk * 32);
        #pragma unroll
        for (int c = 0; c < 8; ++c) {
            bf16x8 bb = *(const bf16x8*)(wbase + c * 16 * XS + kk * 32);
            acc[c] = __builtin_amdgcn_mfma_f32_16x16x32_bf16(a, bb, acc[c], 0, 0, 0);
        }
    }
    float sum[4] = {0.f, 0.f, 0.f, 0.f};
    float ssq[4] = {0.f, 0.f, 0.f, 0.f};
    #pragma unroll
    for (int c = 0; c < 8; ++c) {
        float bias = bp[c * 16 + rsub];
        #pragma unroll
        for (int r = 0; r < 4; ++r) {
            float h = acc[c][r] + bias;
            h = fmaxf(h, 0.0f);
            acc[c][r] = h;
            sum[r] += h;
            ssq[r] += h * h;
        }
    }
    #pragma unroll
    for (int msk = 1; msk < 16; msk <<= 1) {
        #pragma unroll
        for (int r = 0; r < 4; ++r) {
            sum[r] += __shfl_xor(sum[r], msk);
            ssq[r] += __shfl_xor(ssq[r], msk);
        }
    }
    #pragma unroll
    for (int r = 0; r < 4; ++r) {
        int n = n0 + wv * 16 + g * 4 + r;
        if (n >= N) continue;
        float mean = sum[r] * (1.0f / 128.0f);
        float var = ssq[r] * (1.0f / 128.0f) - mean * mean + EPSV;
        float inv = rsqrtf(var);
        float* orow = out + (long)n * OUT_STRIDE + ocol;
        #pragma unroll
        for (int c = 0; c < 8; ++c) {
            int col = c * 16 + rsub;
            __builtin_nontemporal_store((acc[c][r] - mean) * sp[col] * inv + op[col], &orow[col]);
        }
    }
}

// ---------------- transform: all 3 hops from bf16 rows, 2 row-tiles per block ----------------
__global__ __launch_bounds__(256)
void transform3_kernel(const unsigned short* __restrict__ featb,
                       const unsigned short* __restrict__ h1b,
                       const unsigned short* __restrict__ h2b,
                       const float* __restrict__ Wf,
                       const float* __restrict__ bf, const float* __restrict__ scf,
                       const float* __restrict__ offp,
                       float* out, int N)
{
    const int hop = blockIdx.y;
    const int tid = threadIdx.x;
    __shared__ __attribute__((aligned(16))) short Wl[128 * XS];
    __shared__ __attribute__((aligned(16))) short Xl[64 * XS];
    stage_W(Wf + (long)hop * 128 * 128, Wl, tid);
    const unsigned short* xb = (hop == 0) ? featb : (hop == 1) ? h1b : h2b;
    #pragma unroll
    for (int t2 = 0; t2 < 2; ++t2) {
        const int n0 = (blockIdx.x * 2 + t2) * 64;
        for (int idx = tid; idx < 64 * 16; idx += 256) {
            int r = idx >> 4;
            int c = (idx & 15) * 8;
            int n = n0 + r;
            int4 v = make_int4(0, 0, 0, 0);
            if (n < N) v = *(const int4*)(xb + (long)n * 128 + c);
            *(int4*)&Xl[r * XS + c] = v;
        }
        __syncthreads();
        mfma_ln_epilogue(Xl, Wl, bf + hop * 128, scf + hop * 128, offp + hop * 128,
                         out, hop * 128, n0, N, tid);
        __syncthreads();
    }
}

// ---------------- fallback: push scatter + generic transform ----------------
__global__ __launch_bounds__(256)
void scatter_kernel(const float* X, long xstride, long xcol0,
                    const int* __restrict__ src, const int* __restrict__ dst,
                    const float* __restrict__ w, const float* __restrict__ Dn,
                    int useDn, float* out, long ocol0, int nE)
{
    const int lane = threadIdx.x & 63;
    const int wave = (int)((blockIdx.x * blockDim.x + threadIdx.x) >> 6);
    const int nWaves = (int)((gridDim.x * blockDim.x) >> 6);
    for (int e = wave; e < nE; e += nWaves) {
        const int s = src[e];
        const int d = dst[e];
        float ww = w[e];
        if (useDn) ww *= Dn[s];
        const float2 v = *(const float2*)(X + (long)s * xstride + xcol0 + 2 * lane);
        float* o = out + (long)d * OUT_STRIDE + ocol0 + 2 * lane;
        atomicAdd(o, v.x * ww);
        atomicAdd(o + 1, v.y * ww);
    }
}

__global__ __launch_bounds__(256)
void transform_f32_kernel(const float* x, long xs, int useDnIn,
                          const float* __restrict__ Dn,
                          const float* __restrict__ Wf_hop,
                          const float* __restrict__ bp, const float* __restrict__ sp,
                          const float* __restrict__ op,
                          float* out, int ocol, int N)
{
    __shared__ __attribute__((aligned(16))) short Wl[128 * XS];
    __shared__ __attribute__((aligned(16))) short Xl[64 * XS];
    const int tid = threadIdx.x;
    stage_W(Wf_hop, Wl, tid);
    const int n0 = blockIdx.x * 64;
    for (int idx = tid; idx < 64 * 32; idx += 256) {
        int r = idx >> 5;
        int col = (idx & 31) * 4;
        int n = n0 + r;
        float4 v = make_float4(0.f, 0.f, 0.f, 0.f);
        float m = 1.0f;
        if (n < N) {
            v = *(const float4*)(x + (long)n * xs + col);
            if (useDnIn) m = Dn[n];
        }
        short* p = &Xl[r * XS + col];
        p[0] = f2bf(v.x * m); p[1] = f2bf(v.y * m); p[2] = f2bf(v.z * m); p[3] = f2bf(v.w * m);
    }
    __syncthreads();
    mfma_ln_epilogue(Xl, Wl, bp, sp, op, out, ocol, n0, N, tid);
}

extern "C" void kernel_launch(void* const* d_in, const int* in_sizes, int n_in,
                              void* d_out, int out_size, void* d_ws, size_t ws_size,
                              hipStream_t stream) {
    const float* features = (const float*)d_in[0];
    const int*   src      = (const int*)d_in[1];
    const int*   dst      = (const int*)d_in[2];
    const float* w        = (const float*)d_in[3];
    const float* Dn       = (const float*)d_in[4];
    const float* W        = (const float*)d_in[5];
    const float* b        = (const float*)d_in[6];
    const float* scale    = (const float*)d_in[7];
    const float* offset   = (const float*)d_in[8];
    float* out = (float*)d_out;
    const int N = in_sizes[0] / 128;
    const int E = in_sizes[1];
    const int NB = (N + BS - 1) >> BSH;
    const int nblk = (N + 63) / 64;
    int CAP = ((E / (NB > 0 ? NB : 1)) * 3 / 2 + 255) & ~255;
    if (CAP < 1024) CAP = 1024;
    const size_t NC = (size_t)NB * CAP;

    // ws layout (ints): off[N] deg[N] | ed[2NC] | bcur[NB] | edw[2NC] | dlu[NC/2] | featb[64N] h1b[64N] h2b[64N]
    const size_t o_off = 0;
    const size_t o_deg = (size_t)N;
    const size_t o_ed  = ((size_t)2 * N + 3) & ~(size_t)3;
    const size_t o_bc  = o_ed + 2 * NC;
    const size_t o_un  = (o_bc + NB + 3) & ~(size_t)3;
    const size_t o_dl  = o_un + 2 * NC;
    const size_t o_fb  = (o_dl + (NC + 1) / 2 + 3) & ~(size_t)3;
    const size_t need  = (o_fb + 3 * (size_t)64 * N) * 4;

    if (NB <= NBMAX && ws_size >= need) {
        int* ws_i  = (int*)d_ws;
        int* off   = ws_i + o_off;
        int* deg   = ws_i + o_deg;
        int2* ed   = (int2*)(ws_i + o_ed);
        int* bcur  = ws_i + o_bc;
        int2* edw  = (int2*)(ws_i + o_un);
        unsigned short* dlu = (unsigned short*)(ws_i + o_dl);
        unsigned short* featb = (unsigned short*)(ws_i + o_fb);
        unsigned short* h1b   = featb + (size_t)N * 128;
        unsigned short* h2b   = h1b + (size_t)N * 128;

        hipMemsetAsync(bcur, 0, (size_t)NB * 4, stream);
        multisplit_pack_kernel<<<(E + CH - 1) / CH, 256, 0, stream>>>(
            src, dst, w, bcur, edw, dlu, E, CAP, features, featb, (long)N * 32);
        bucket_csr_kernel<<<NB, 256, 0, stream>>>(edw, dlu, bcur, off, deg, ed, N, CAP);

        gather_wave<<<(N + 3) / 4, 256, 0, stream>>>(featb, off, deg, ed, Dn, h1b, N);
        gather_wave<<<(N + 3) / 4, 256, 0, stream>>>(h1b, off, deg, ed, Dn, h2b, N);

        dim3 tg((N + 127) / 128, 3);
        transform3_kernel<<<tg, 256, 0, stream>>>(featb, h1b, h2b, W, b, scale, offset, out, N);
    } else {
        // fallback: atomic scatter path (raw agg stored; Dn applied on read)
        hipMemsetAsync(out, 0, (size_t)out_size * sizeof(float), stream);
        scatter_kernel<<<2048, 256, 0, stream>>>(features, 128, 0, src, dst, w, Dn, 0, out, 128, E);
        scatter_kernel<<<2048, 256, 0, stream>>>(out, OUT_STRIDE, 128, src, dst, w, Dn, 1, out, 256, E);
        transform_f32_kernel<<<nblk, 256, 0, stream>>>(features, 128, 0, Dn, W, b, scale, offset, out, 0, N);
        transform_f32_kernel<<<nblk, 256, 0, stream>>>(out + 128, OUT_STRIDE, 1, Dn, W + 128 * 128, b + 128, scale + 128, offset + 128, out, 128, N);
        transform_f32_kernel<<<nblk, 256, 0, stream>>>(out + 256, OUT_STRIDE, 1, Dn, W + 2 * 128 * 128, b + 256, scale + 256, offset + 256, out, 256, N);
    }
}

// Round 15
// 302.403 us; speedup vs baseline: 1.1650x; 1.0132x over previous
//
#include <hip/hip_runtime.h>
#include <hip/hip_bf16.h>

#define OUT_STRIDE 384
#define EPSV 1e-9f
#define BSH 9
#define BS 512             // nodes per bucket
#define NBMAX 512
#define CH 4096            // edges per multisplit chunk
#define XS 136
#define NSL 8              // src slices (L2-sized: 16K rows x 256B = 4MB)
#define SLSH 14

typedef __attribute__((ext_vector_type(8))) short bf16x8;
typedef __attribute__((ext_vector_type(4))) float f32x4;

static __device__ __forceinline__ unsigned short f2bf(float f) {
    __hip_bfloat16 h = __float2bfloat16(f);
    return *reinterpret_cast<unsigned short*>(&h);
}

// ---------------- multisplit (fixed-capacity buckets) + feature pack ----------------
__global__ __launch_bounds__(256)
void multisplit_pack_kernel(const int* __restrict__ src, const int* __restrict__ dst,
                            const float* __restrict__ w, int* __restrict__ bcur,
                            int2* __restrict__ edw, unsigned short* __restrict__ dlu,
                            int E, int CAP,
                            const float* __restrict__ features,
                            unsigned short* __restrict__ featb, long n4) {
    __shared__ int hist[NBMAX], scan_[NBMAX], gbase[NBMAX], lcur[NBMAX];
    __shared__ int recS[CH * 3];
    __shared__ int wt[4];
    const int t = threadIdx.x;
    const int lane = t & 63, wv = t >> 6;
    const int c0 = blockIdx.x * CH;
    const int cnt_total = min(CH, E - c0);

    for (int i = t; i < NBMAX; i += 256) hist[i] = 0;
    __syncthreads();
    #pragma unroll
    for (int p = 0; p < CH / 256; ++p) {
        int i = c0 + p * 256 + t;
        if (i < E) atomicAdd(&hist[dst[i] >> BSH], 1);
    }
    __syncthreads();
    {   // exclusive scan of hist[0..NBMAX)
        int b0 = 2 * t, b1 = 2 * t + 1;
        int h0 = hist[b0], h1 = hist[b1];
        int s = h0 + h1;
        int inc = s;
        #pragma unroll
        for (int d = 1; d < 64; d <<= 1) { int u = __shfl_up(inc, d); if (lane >= d) inc += u; }
        if (lane == 63) wt[wv] = inc;
        __syncthreads();
        int base = 0;
        for (int w2 = 0; w2 < wv; ++w2) base += wt[w2];
        int ex = base + inc - s;
        scan_[b0] = ex;
        scan_[b1] = ex + h0;
    }
    __syncthreads();
    for (int i = t; i < NBMAX; i += 256) {
        if (hist[i] > 0) gbase[i] = atomicAdd(&bcur[i], hist[i]);
        lcur[i] = scan_[i];
    }
    __syncthreads();
    #pragma unroll
    for (int p = 0; p < CH / 256; ++p) {
        int i = c0 + p * 256 + t;
        if (i < E) {
            int d = dst[i];
            int b = d >> BSH;
            int j = atomicAdd(&lcur[b], 1);
            recS[3 * j]     = src[i];
            recS[3 * j + 1] = d;
            recS[3 * j + 2] = __float_as_int(w[i]);
        }
    }
    __syncthreads();
    #pragma unroll
    for (int p = 0; p < CH / 256; ++p) {
        int j = p * 256 + t;
        if (j < cnt_total) {
            int d = recS[3 * j + 1];
            int b = d >> BSH;
            int g = gbase[b] + (j - scan_[b]);
            if (g < CAP) {                         // overflow clamp (deterministic)
                long gp = (long)b * CAP + g;
                edw[gp] = make_int2(recS[3 * j], recS[3 * j + 2]);
                dlu[gp] = (unsigned short)(d - (b << BSH));
            }
        }
    }
    // independent stream: pack features f32 -> bf16
    long gid = blockIdx.x * blockDim.x + threadIdx.x;
    long stride = (long)gridDim.x * blockDim.x;
    for (long p = gid; p < n4; p += stride) {
        float4 v = ((const float4*)features)[p];
        ushort4 o;
        o.x = f2bf(v.x); o.y = f2bf(v.y); o.z = f2bf(v.z); o.w = f2bf(v.w);
        *(ushort4*)&featb[p * 4] = o;
    }
}

// ---------------- per-bucket CSR build, SLICE-ORDERED per node ----------------
// per-(node,slice) counting sort: each node's final edge list is grouped by src>>SLSH,
// so concurrent gather waves touch ~one 4MB X-slice at a time (XCD-L2-resident).
__global__ __launch_bounds__(256)
void bucket_csr_kernel(const int2* __restrict__ edw, const unsigned short* __restrict__ dlu,
                       const int* __restrict__ bcur,
                       int* __restrict__ off, int* __restrict__ deg,
                       int2* __restrict__ ed, int N, int CAP) {
    __shared__ int h[BS * NSL];      // 4096 ints: hist -> exclusive scan -> cursors
    __shared__ int wt[4];
    const int b = blockIdx.x;
    const int t = threadIdx.x;
    const int lane = t & 63, wv = t >> 6;
    const int cnt = min(bcur[b], CAP);
    const long base = (long)b * CAP;
    const int n0 = b << BSH;
    const int nn = min(BS, N - n0);

    for (int i = t; i < BS * NSL; i += 256) h[i] = 0;
    __syncthreads();
    for (int i = t; i < cnt; i += 256) {
        int2 e = edw[base + i];
        int sl = min(e.x >> SLSH, NSL - 1);
        atomicAdd(&h[dlu[base + i] * NSL + sl], 1);
    }
    __syncthreads();
    {   // exclusive scan of h[0..BS*NSL), 16 keys per thread (key order = tid order)
        const int k0 = 16 * t;
        int s = 0;
        #pragma unroll
        for (int k = 0; k < 16; ++k) s += h[k0 + k];
        int inc = s;
        #pragma unroll
        for (int d = 1; d < 64; d <<= 1) { int u = __shfl_up(inc, d); if (lane >= d) inc += u; }
        if (lane == 63) wt[wv] = inc;
        __syncthreads();
        int bpre = 0;
        for (int w2 = 0; w2 < wv; ++w2) bpre += wt[w2];
        int run = bpre + inc - s;
        #pragma unroll
        for (int k = 0; k < 16; ++k) { int tmp = h[k0 + k]; h[k0 + k] = run; run += tmp; }
    }
    __syncthreads();
    // off/deg from slice-scan boundaries: thread t owns local nodes 2t, 2t+1
    {
        #pragma unroll
        for (int q = 0; q < 2; ++q) {
            int j = 2 * t + q;
            if (j < nn) {
                int st = h[j * NSL];
                int en = (j * NSL + NSL < BS * NSL) ? h[j * NSL + NSL] : cnt;
                off[n0 + j] = (int)(base + st);
                deg[n0 + j] = en - st;
            }
        }
    }
    __syncthreads();
    for (int i = t; i < cnt; i += 256) {
        int2 e = edw[base + i];
        int sl = min(e.x >> SLSH, NSL - 1);
        int pos = atomicAdd(&h[dlu[base + i] * NSL + sl], 1);
        ed[base + pos] = e;
    }
}

// ---------------- gather: one wave per node, 4-way split, 4-wide unroll ----------------
// ed/off/deg are single-use cold streams -> nontemporal loads keep L2 for the row table X.
__device__ __forceinline__ void acc8(float* a, int4 r, float w) {
    #pragma unroll
    for (int j = 0; j < 4; ++j) {
        int bits = (&r.x)[j];
        float f0 = __int_as_float(bits << 16);
        float f1 = __int_as_float(bits & 0xffff0000);
        a[2 * j]     += f0 * w;
        a[2 * j + 1] += f1 * w;
    }
}

__device__ __forceinline__ int2 nt_ld_int2(const int2* p) {
    long v = __builtin_nontemporal_load((const long*)p);
    int2 r; r.x = (int)(v & 0xffffffffL); r.y = (int)(((unsigned long)v) >> 32);
    return r;
}

__global__ __launch_bounds__(256)
void gather_wave(const unsigned short* __restrict__ X,
                 const int* __restrict__ off, const int* __restrict__ deg,
                 const int2* __restrict__ ed,
                 const float* __restrict__ Dn,
                 unsigned short* __restrict__ outb, int N) {
    const int tid = threadIdx.x;
    const int n = blockIdx.x * 4 + (tid >> 6);    // one wave per node
    if (n >= N) return;
    const int lane = tid & 63;
    const int g2 = lane >> 4;                     // 0..3 edge-split group
    const int l = lane & 15;                      // 16 lanes x 16B = 256B row
    const int beg = __builtin_nontemporal_load(&off[n]);
    const int end = beg + __builtin_nontemporal_load(&deg[n]);
    float a[8] = {0.f, 0.f, 0.f, 0.f, 0.f, 0.f, 0.f, 0.f};
    const unsigned short* Xc = X + 8 * l;
    int i = beg + g2;
    for (; i + 12 < end; i += 16) {               // 4 edges per group in flight
        int2 e0 = nt_ld_int2(&ed[i]);
        int2 e1 = nt_ld_int2(&ed[i + 4]);
        int2 e2 = nt_ld_int2(&ed[i + 8]);
        int2 e3 = nt_ld_int2(&ed[i + 12]);
        int4 r0 = *(const int4*)(Xc + (long)e0.x * 128);
        int4 r1 = *(const int4*)(Xc + (long)e1.x * 128);
        int4 r2 = *(const int4*)(Xc + (long)e2.x * 128);
        int4 r3 = *(const int4*)(Xc + (long)e3.x * 128);
        acc8(a, r0, __int_as_float(e0.y));
        acc8(a, r1, __int_as_float(e1.y));
        acc8(a, r2, __int_as_float(e2.y));
        acc8(a, r3, __int_as_float(e3.y));
    }
    for (; i < end; i += 4) {
        int2 e0 = nt_ld_int2(&ed[i]);
        int4 r0 = *(const int4*)(Xc + (long)e0.x * 128);
        acc8(a, r0, __int_as_float(e0.y));
    }
    #pragma unroll
    for (int j = 0; j < 8; ++j) {
        a[j] += __shfl_xor(a[j], 16);
        a[j] += __shfl_xor(a[j], 32);
    }
    if (g2 == 0) {
        const float dn = Dn[n];
        int4 o;
        #pragma unroll
        for (int j = 0; j < 4; ++j) {
            unsigned lo = f2bf(a[2 * j] * dn);
            unsigned hi = f2bf(a[2 * j + 1] * dn);
            (&o.x)[j] = (int)((hi << 16) | lo);
        }
        *(int4*)&outb[(long)n * 128 + 8 * l] = o;
    }
}

// ---------------- shared MFMA + LN epilogue ----------------
__device__ __forceinline__ void stage_W(const float* __restrict__ Wf_hop, short* Wl, int tid) {
    const float4* W4 = (const float4*)Wf_hop;
    for (int idx = tid; idx < 128 * 32; idx += 256) {
        float4 v = W4[idx];
        int row = idx >> 5;
        int col = (idx & 31) * 4;
        short* p = &Wl[row * XS + col];
        p[0] = f2bf(v.x); p[1] = f2bf(v.y); p[2] = f2bf(v.z); p[3] = f2bf(v.w);
    }
}

__device__ __forceinline__ void mfma_ln_epilogue(
    const short* Xl, const short* Wl,
    const float* __restrict__ bp, const float* __restrict__ sp, const float* __restrict__ op,
    float* out, int ocol, int n0, int N, int tid)
{
    const int lane = tid & 63;
    const int wv = tid >> 6;
    f32x4 acc[8];
    #pragma unroll
    for (int c = 0; c < 8; ++c) acc[c] = (f32x4){0.f, 0.f, 0.f, 0.f};
    const int rsub = lane & 15;
    const int g = lane >> 4;
    const short* xbase = &Xl[(wv * 16 + rsub) * XS + g * 8];
    const short* wbase = &Wl[rsub * XS + g * 8];
    #pragma unroll
    for (int kk = 0; kk < 4; ++kk) {
        bf16x8 a = *(const bf16x8*)(xbase + kk * 32);
        #pragma unroll
        for (int c = 0; c < 8; ++c) {
            bf16x8 bb = *(const bf16x8*)(wbase + c * 16 * XS + kk * 32);
            acc[c] = __builtin_amdgcn_mfma_f32_16x16x32_bf16(a, bb, acc[c], 0, 0, 0);
        }
    }
    float sum[4] = {0.f, 0.f, 0.f, 0.f};
    float ssq[4] = {0.f, 0.f, 0.f, 0.f};
    #pragma unroll
    for (int c = 0; c < 8; ++c) {
        float bias = bp[c * 16 + rsub];
        #pragma unroll
        for (int r = 0; r < 4; ++r) {
            float h = acc[c][r] + bias;
            h = fmaxf(h, 0.0f);
            acc[c][r] = h;
            sum[r] += h;
            ssq[r] += h * h;
        }
    }
    #pragma unroll
    for (int msk = 1; msk < 16; msk <<= 1) {
        #pragma unroll
        for (int r = 0; r < 4; ++r) {
            sum[r] += __shfl_xor(sum[r], msk);
            ssq[r] += __shfl_xor(ssq[r], msk);
        }
    }
    #pragma unroll
    for (int r = 0; r < 4; ++r) {
        int n = n0 + wv * 16 + g * 4 + r;
        if (n >= N) continue;
        float mean = sum[r] * (1.0f / 128.0f);
        float var = ssq[r] * (1.0f / 128.0f) - mean * mean + EPSV;
        float inv = rsqrtf(var);
        float* orow = out + (long)n * OUT_STRIDE + ocol;
        #pragma unroll
        for (int c = 0; c < 8; ++c) {
            int col = c * 16 + rsub;
            __builtin_nontemporal_store((acc[c][r] - mean) * sp[col] * inv + op[col], &orow[col]);
        }
    }
}

// ---------------- transform: all 3 hops from bf16 rows, 2 row-tiles per block ----------------
__global__ __launch_bounds__(256)
void transform3_kernel(const unsigned short* __restrict__ featb,
                       const unsigned short* __restrict__ h1b,
                       const unsigned short* __restrict__ h2b,
                       const float* __restrict__ Wf,
                       const float* __restrict__ bf, const float* __restrict__ scf,
                       const float* __restrict__ offp,
                       float* out, int N)
{
    const int hop = blockIdx.y;
    const int tid = threadIdx.x;
    __shared__ __attribute__((aligned(16))) short Wl[128 * XS];
    __shared__ __attribute__((aligned(16))) short Xl[64 * XS];
    stage_W(Wf + (long)hop * 128 * 128, Wl, tid);
    const unsigned short* xb = (hop == 0) ? featb : (hop == 1) ? h1b : h2b;
    #pragma unroll
    for (int t2 = 0; t2 < 2; ++t2) {
        const int n0 = (blockIdx.x * 2 + t2) * 64;
        for (int idx = tid; idx < 64 * 16; idx += 256) {
            int r = idx >> 4;
            int c = (idx & 15) * 8;
            int n = n0 + r;
            int4 v = make_int4(0, 0, 0, 0);
            if (n < N) v = *(const int4*)(xb + (long)n * 128 + c);
            *(int4*)&Xl[r * XS + c] = v;
        }
        __syncthreads();
        mfma_ln_epilogue(Xl, Wl, bf + hop * 128, scf + hop * 128, offp + hop * 128,
                         out, hop * 128, n0, N, tid);
        __syncthreads();
    }
}

// ---------------- fallback: push scatter + generic transform ----------------
__global__ __launch_bounds__(256)
void scatter_kernel(const float* X, long xstride, long xcol0,
                    const int* __restrict__ src, const int* __restrict__ dst,
                    const float* __restrict__ w, const float* __restrict__ Dn,
                    int useDn, float* out, long ocol0, int nE)
{
    const int lane = threadIdx.x & 63;
    const int wave = (int)((blockIdx.x * blockDim.x + threadIdx.x) >> 6);
    const int nWaves = (int)((gridDim.x * blockDim.x) >> 6);
    for (int e = wave; e < nE; e += nWaves) {
        const int s = src[e];
        const int d = dst[e];
        float ww = w[e];
        if (useDn) ww *= Dn[s];
        const float2 v = *(const float2*)(X + (long)s * xstride + xcol0 + 2 * lane);
        float* o = out + (long)d * OUT_STRIDE + ocol0 + 2 * lane;
        atomicAdd(o, v.x * ww);
        atomicAdd(o + 1, v.y * ww);
    }
}

__global__ __launch_bounds__(256)
void transform_f32_kernel(const float* x, long xs, int useDnIn,
                          const float* __restrict__ Dn,
                          const float* __restrict__ Wf_hop,
                          const float* __restrict__ bp, const float* __restrict__ sp,
                          const float* __restrict__ op,
                          float* out, int ocol, int N)
{
    __shared__ __attribute__((aligned(16))) short Wl[128 * XS];
    __shared__ __attribute__((aligned(16))) short Xl[64 * XS];
    const int tid = threadIdx.x;
    stage_W(Wf_hop, Wl, tid);
    const int n0 = blockIdx.x * 64;
    for (int idx = tid; idx < 64 * 32; idx += 256) {
        int r = idx >> 5;
        int col = (idx & 31) * 4;
        int n = n0 + r;
        float4 v = make_float4(0.f, 0.f, 0.f, 0.f);
        float m = 1.0f;
        if (n < N) {
            v = *(const float4*)(x + (long)n * xs + col);
            if (useDnIn) m = Dn[n];
        }
        short* p = &Xl[r * XS + col];
        p[0] = f2bf(v.x * m); p[1] = f2bf(v.y * m); p[2] = f2bf(v.z * m); p[3] = f2bf(v.w * m);
    }
    __syncthreads();
    mfma_ln_epilogue(Xl, Wl, bp, sp, op, out, ocol, n0, N, tid);
}

extern "C" void kernel_launch(void* const* d_in, const int* in_sizes, int n_in,
                              void* d_out, int out_size, void* d_ws, size_t ws_size,
                              hipStream_t stream) {
    const float* features = (const float*)d_in[0];
    const int*   src      = (const int*)d_in[1];
    const int*   dst      = (const int*)d_in[2];
    const float* w        = (const float*)d_in[3];
    const float* Dn       = (const float*)d_in[4];
    const float* W        = (const float*)d_in[5];
    const float* b        = (const float*)d_in[6];
    const float* scale    = (const float*)d_in[7];
    const float* offset   = (const float*)d_in[8];
    float* out = (float*)d_out;
    const int N = in_sizes[0] / 128;
    const int E = in_sizes[1];
    const int NB = (N + BS - 1) >> BSH;
    const int nblk = (N + 63) / 64;
    int CAP = ((E / (NB > 0 ? NB : 1)) * 3 / 2 + 255) & ~255;
    if (CAP < 1024) CAP = 1024;
    const size_t NC = (size_t)NB * CAP;

    // ws layout (ints): off[N] deg[N] | ed[2NC] | bcur[NB] | edw[2NC] | dlu[NC/2] | featb[64N] h1b[64N] h2b[64N]
    const size_t o_off = 0;
    const size_t o_deg = (size_t)N;
    const size_t o_ed  = ((size_t)2 * N + 3) & ~(size_t)3;
    const size_t o_bc  = o_ed + 2 * NC;
    const size_t o_un  = (o_bc + NB + 3) & ~(size_t)3;
    const size_t o_dl  = o_un + 2 * NC;
    const size_t o_fb  = (o_dl + (NC + 1) / 2 + 3) & ~(size_t)3;
    const size_t need  = (o_fb + 3 * (size_t)64 * N) * 4;

    if (NB <= NBMAX && ws_size >= need) {
        int* ws_i  = (int*)d_ws;
        int* off   = ws_i + o_off;
        int* deg   = ws_i + o_deg;
        int2* ed   = (int2*)(ws_i + o_ed);
        int* bcur  = ws_i + o_bc;
        int2* edw  = (int2*)(ws_i + o_un);
        unsigned short* dlu = (unsigned short*)(ws_i + o_dl);
        unsigned short* featb = (unsigned short*)(ws_i + o_fb);
        unsigned short* h1b   = featb + (size_t)N * 128;
        unsigned short* h2b   = h1b + (size_t)N * 128;

        hipMemsetAsync(bcur, 0, (size_t)NB * 4, stream);
        multisplit_pack_kernel<<<(E + CH - 1) / CH, 256, 0, stream>>>(
            src, dst, w, bcur, edw, dlu, E, CAP, features, featb, (long)N * 32);
        bucket_csr_kernel<<<NB, 256, 0, stream>>>(edw, dlu, bcur, off, deg, ed, N, CAP);

        gather_wave<<<(N + 3) / 4, 256, 0, stream>>>(featb, off, deg, ed, Dn, h1b, N);
        gather_wave<<<(N + 3) / 4, 256, 0, stream>>>(h1b, off, deg, ed, Dn, h2b, N);

        dim3 tg((N + 127) / 128, 3);
        transform3_kernel<<<tg, 256, 0, stream>>>(featb, h1b, h2b, W, b, scale, offset, out, N);
    } else {
        // fallback: atomic scatter path (raw agg stored; Dn applied on read)
        hipMemsetAsync(out, 0, (size_t)out_size * sizeof(float), stream);
        scatter_kernel<<<2048, 256, 0, stream>>>(features, 128, 0, src, dst, w, Dn, 0, out, 128, E);
        scatter_kernel<<<2048, 256, 0, stream>>>(out, OUT_STRIDE, 128, src, dst, w, Dn, 1, out, 256, E);
        transform_f32_kernel<<<nblk, 256, 0, stream>>>(features, 128, 0, Dn, W, b, scale, offset, out, 0, N);
        transform_f32_kernel<<<nblk, 256, 0, stream>>>(out + 128, OUT_STRIDE, 1, Dn, W + 128 * 128, b + 128, scale + 128, offset + 128, out, 128, N);
        transform_f32_kernel<<<nblk, 256, 0, stream>>>(out + 256, OUT_STRIDE, 1, Dn, W + 2 * 128 * 128, b + 256, scale + 256, offset + 256, out, 256, N);
    }
}